// Round 1
// baseline (123.842 us; speedup 1.0000x reference)
//
#include <hip/hip_runtime.h>

#define DIM 128

// K1: s[i] = dot(x[i], a1); deg=1 (self loop), t=0, w=0
__global__ void k_init(const float* __restrict__ x, const float* __restrict__ a1,
                       float* __restrict__ s, float* __restrict__ deg,
                       float* __restrict__ t, float* __restrict__ w, int n) {
    int wave = (blockIdx.x * blockDim.x + threadIdx.x) >> 6;
    int lane = threadIdx.x & 63;
    if (wave >= n) return;
    const float2* xr = (const float2*)(x + (size_t)wave * DIM);
    float2 xv = xr[lane];
    const float2* a1r = (const float2*)a1;
    float2 av = a1r[lane];
    float partial = xv.x * av.x + xv.y * av.y;
    #pragma unroll
    for (int off = 32; off > 0; off >>= 1)
        partial += __shfl_xor(partial, off, 64);
    if (lane == 0) {
        s[wave]   = partial;
        deg[wave] = 1.0f;   // self-loop
        t[wave]   = 0.0f;
        w[wave]   = 0.0f;
    }
}

// K2: degree count of col (edge weights all 1)
__global__ void k_deg(const int* __restrict__ col, float* __restrict__ deg, int E) {
    int tid = blockIdx.x * blockDim.x + threadIdx.x;
    if (tid < E) atomicAdd(&deg[col[tid]], 1.0f);
}

// K3: per-edge scalar scatter: t[r] += norm*s[c]; w[r] += norm
__global__ void k_edge(const int* __restrict__ row, const int* __restrict__ col,
                       const float* __restrict__ s, const float* __restrict__ deg,
                       float* __restrict__ t, float* __restrict__ w, int E) {
    int tid = blockIdx.x * blockDim.x + threadIdx.x;
    if (tid >= E) return;
    int r = row[tid], c = col[tid];
    float norm = rsqrtf(deg[r]) * rsqrtf(deg[c]);
    atomicAdd(&t[r], norm * s[c]);
    atomicAdd(&w[r], norm);
}

// K4: out[i][d] = a2[d]*(t[i] + s[i]/deg[i]) + bias[d]*(w[i] + 1/deg[i])
__global__ void k_out(const float* __restrict__ s, const float* __restrict__ deg,
                      const float* __restrict__ t, const float* __restrict__ w,
                      const float* __restrict__ a2, const float* __restrict__ bias,
                      float* __restrict__ out, int n) {
    int wave = (blockIdx.x * blockDim.x + threadIdx.x) >> 6;
    int lane = threadIdx.x & 63;
    if (wave >= n) return;
    float dis = rsqrtf(deg[wave]);
    float selfn = dis * dis;           // matches ref: deg_inv_sqrt[i]^2
    float tv = t[wave] + selfn * s[wave];
    float wv = w[wave] + selfn;
    float2 a2v = ((const float2*)a2)[lane];
    float2 bv  = ((const float2*)bias)[lane];
    float2 o;
    o.x = a2v.x * tv + bv.x * wv;
    o.y = a2v.y * tv + bv.y * wv;
    ((float2*)(out + (size_t)wave * DIM))[lane] = o;
}

extern "C" void kernel_launch(void* const* d_in, const int* in_sizes, int n_in,
                              void* d_out, int out_size, void* d_ws, size_t ws_size,
                              hipStream_t stream) {
    const float* x    = (const float*)d_in[0];
    const int*   ei   = (const int*)d_in[1];
    const float* a1   = (const float*)d_in[2];
    const float* a2   = (const float*)d_in[3];
    const float* bias = (const float*)d_in[4];
    float* out = (float*)d_out;

    int N = in_sizes[0] / DIM;
    int E = in_sizes[1] / 2;
    const int* row = ei;        // edge_index[0]
    const int* col = ei + E;    // edge_index[1]

    float* s   = (float*)d_ws;
    float* deg = s + N;
    float* t   = deg + N;
    float* w   = t + N;

    // K1: wave per node
    {
        int waves_per_block = 4;                 // 256 threads
        int blocks = (N + waves_per_block - 1) / waves_per_block;
        k_init<<<blocks, 256, 0, stream>>>(x, a1, s, deg, t, w, N);
    }
    // K2: degree
    k_deg<<<(E + 255) / 256, 256, 0, stream>>>(col, deg, E);
    // K3: edge scatter
    k_edge<<<(E + 255) / 256, 256, 0, stream>>>(row, col, s, deg, t, w, E);
    // K4: output
    {
        int blocks = (N + 3) / 4;
        k_out<<<blocks, 256, 0, stream>>>(s, deg, t, w, a2, bias, out, N);
    }
}

// Round 2
// 117.446 us; speedup vs baseline: 1.0545x; 1.0545x over previous
//
#include <hip/hip_runtime.h>

#define DIM 128
#define NXCD 8

// HW_REG_XCC_ID = 20, bits [3:0]
__device__ __forceinline__ unsigned get_xcd() {
    return __builtin_amdgcn_s_getreg((20) | (0 << 6) | ((4 - 1) << 11)) & (NXCD - 1);
}

// K1: s[i] = dot(x[i], a1)  (wave per node, coalesced float2)
__global__ void k_s(const float* __restrict__ x, const float* __restrict__ a1,
                    float* __restrict__ s, int n) {
    int wave = (blockIdx.x * blockDim.x + threadIdx.x) >> 6;
    int lane = threadIdx.x & 63;
    if (wave >= n) return;
    float2 xv = ((const float2*)(x + (size_t)wave * DIM))[lane];
    float2 av = ((const float2*)a1)[lane];
    float partial = xv.x * av.x + xv.y * av.y;
    #pragma unroll
    for (int off = 32; off > 0; off >>= 1)
        partial += __shfl_xor(partial, off, 64);
    if (lane == 0) s[wave] = partial;
}

// K2: per-XCD degree partials of col (L2-local atomics)
__global__ void k_deg(const int* __restrict__ col, unsigned* __restrict__ degp,
                      int E, int n) {
    int tid = blockIdx.x * blockDim.x + threadIdx.x;
    if (tid >= E) return;
    unsigned xcd = get_xcd();
    __hip_atomic_fetch_add(&degp[(size_t)xcd * n + col[tid]], 1u,
                           __ATOMIC_RELAXED, __HIP_MEMORY_SCOPE_WORKGROUP);
}

// K3: deg = 1 + sum(partials); dis = rsqrt(deg); sdis = dis*s
__global__ void k_combine(const unsigned* __restrict__ degp, const float* __restrict__ s,
                          float* __restrict__ dis, float* __restrict__ sdis, int n) {
    int i = blockIdx.x * blockDim.x + threadIdx.x;
    if (i >= n) return;
    unsigned d = 1u;  // self-loop
    #pragma unroll
    for (int x = 0; x < NXCD; ++x) d += degp[(size_t)x * n + i];
    float dv = rsqrtf((float)d);
    dis[i] = dv;
    sdis[i] = dv * s[i];
}

// K4: per-edge scatter into per-XCD partials (L2-local atomics)
//     vp[r] += dis[c]*s[c] ; up[r] += dis[c]
__global__ void k_edge(const int* __restrict__ row, const int* __restrict__ col,
                       const float* __restrict__ dis, const float* __restrict__ sdis,
                       float* __restrict__ up, float* __restrict__ vp, int E, int n) {
    int tid = blockIdx.x * blockDim.x + threadIdx.x;
    if (tid >= E) return;
    unsigned xcd = get_xcd();
    int r = row[tid], c = col[tid];
    size_t base = (size_t)xcd * n;
    __hip_atomic_fetch_add(&vp[base + r], sdis[c],
                           __ATOMIC_RELAXED, __HIP_MEMORY_SCOPE_WORKGROUP);
    __hip_atomic_fetch_add(&up[base + r], dis[c],
                           __ATOMIC_RELAXED, __HIP_MEMORY_SCOPE_WORKGROUP);
}

// K5: T[i] = dis*Σvp + dis^2*s ; W[i] = dis*Σup + dis^2   (self-loop folded in)
__global__ void k_tw(const float* __restrict__ up, const float* __restrict__ vp,
                     const float* __restrict__ dis, const float* __restrict__ s,
                     float* __restrict__ T, float* __restrict__ W, int n) {
    int i = blockIdx.x * blockDim.x + threadIdx.x;
    if (i >= n) return;
    float sv = 0.f, sw = 0.f;
    #pragma unroll
    for (int x = 0; x < NXCD; ++x) {
        sv += vp[(size_t)x * n + i];
        sw += up[(size_t)x * n + i];
    }
    float d = dis[i];
    T[i] = d * sv + d * d * s[i];
    W[i] = d * sw + d * d;
}

// K6: out[i][d] = a2[d]*T[i] + bias[d]*W[i]
__global__ void k_out(const float* __restrict__ T, const float* __restrict__ W,
                      const float* __restrict__ a2, const float* __restrict__ bias,
                      float* __restrict__ out, int n) {
    int wave = (blockIdx.x * blockDim.x + threadIdx.x) >> 6;
    int lane = threadIdx.x & 63;
    if (wave >= n) return;
    float tv = T[wave], wv = W[wave];
    float2 a2v = ((const float2*)a2)[lane];
    float2 bv  = ((const float2*)bias)[lane];
    float2 o;
    o.x = a2v.x * tv + bv.x * wv;
    o.y = a2v.y * tv + bv.y * wv;
    ((float2*)(out + (size_t)wave * DIM))[lane] = o;
}

extern "C" void kernel_launch(void* const* d_in, const int* in_sizes, int n_in,
                              void* d_out, int out_size, void* d_ws, size_t ws_size,
                              hipStream_t stream) {
    const float* x    = (const float*)d_in[0];
    const int*   ei   = (const int*)d_in[1];
    const float* a1   = (const float*)d_in[2];
    const float* a2   = (const float*)d_in[3];
    const float* bias = (const float*)d_in[4];
    float* out = (float*)d_out;

    int N = in_sizes[0] / DIM;
    int E = in_sizes[1] / 2;
    const int* row = ei;        // edge_index[0]
    const int* col = ei + E;    // edge_index[1]

    // workspace layout (floats): s, dis, sdis, T, W, then zeroed region:
    // degp[8][N] (uint), up[8][N], vp[8][N]
    float* s    = (float*)d_ws;
    float* dis  = s + N;
    float* sdis = dis + N;
    float* T    = sdis + N;
    float* W    = T + N;
    unsigned* degp = (unsigned*)(W + N);
    float* up   = (float*)(degp + (size_t)NXCD * N);
    float* vp   = up + (size_t)NXCD * N;

    // zero the 24*N partial region in one async memset (graph-capture safe)
    hipMemsetAsync(degp, 0, (size_t)3 * NXCD * N * sizeof(float), stream);

    k_s<<<(N + 3) / 4, 256, 0, stream>>>(x, a1, s, N);
    k_deg<<<(E + 255) / 256, 256, 0, stream>>>(col, degp, E, N);
    k_combine<<<(N + 255) / 256, 256, 0, stream>>>(degp, s, dis, sdis, N);
    k_edge<<<(E + 255) / 256, 256, 0, stream>>>(row, col, dis, sdis, up, vp, E, N);
    k_tw<<<(N + 255) / 256, 256, 0, stream>>>(up, vp, dis, s, T, W, N);
    k_out<<<(N + 3) / 4, 256, 0, stream>>>(T, W, a2, bias, out, N);
}

// Round 3
// 70.620 us; speedup vs baseline: 1.7536x; 1.6631x over previous
//
#include <hip/hip_runtime.h>

#define DIM 128
#define RA 4            // node ranges for degree histogram (12500 nodes, 50KB uint LDS)
#define RB 8            // node ranges for edge accumulation (6250 nodes, 2x25KB f32 LDS)
#define NRA 12500
#define NRB 6250

// K1: s[i] = dot(x[i], a1)  (wave per node, coalesced float2)
__global__ void k_s(const float* __restrict__ x, const float* __restrict__ a1,
                    float* __restrict__ s, int n) {
    int wave = (blockIdx.x * blockDim.x + threadIdx.x) >> 6;
    int lane = threadIdx.x & 63;
    if (wave >= n) return;
    float2 xv = ((const float2*)(x + (size_t)wave * DIM))[lane];
    float2 av = ((const float2*)a1)[lane];
    float partial = xv.x * av.x + xv.y * av.y;
    #pragma unroll
    for (int off = 32; off > 0; off >>= 1)
        partial += __shfl_xor(partial, off, 64);
    if (lane == 0) s[wave] = partial;
}

// K2: degree histogram of col, LDS-privatized per (chunk, range) block.
// Block (c,r): LDS-count edges in chunk c whose col is in range r, then write
// the whole slice to pA[c][range] with plain coalesced stores.
__global__ __launch_bounds__(1024) void k_histA(const int* __restrict__ col,
                                                unsigned* __restrict__ pA,
                                                int E, int N, int C) {
    __shared__ unsigned cnt[NRA];
    int c = blockIdx.x / RA;
    int r = blockIdx.x % RA;
    int lo = r * NRA;
    int hi = lo + NRA; if (hi > N) hi = N;
    int len = hi - lo;
    for (int j = threadIdx.x; j < len; j += 1024) cnt[j] = 0u;
    __syncthreads();
    int per = (E + C - 1) / C;
    int e0 = c * per;
    int e1 = e0 + per; if (e1 > E) e1 = E;
    for (int e = e0 + threadIdx.x; e < e1; e += 1024) {
        unsigned idx = (unsigned)(col[e] - lo);
        if (idx < (unsigned)len) atomicAdd(&cnt[idx], 1u);
    }
    __syncthreads();
    unsigned* dst = pA + (size_t)c * N + lo;
    for (int j = threadIdx.x; j < len; j += 1024) dst[j] = cnt[j];
}

// K3: deg = 1 + sum_c pA[c][i]; sd[i] = (dis, dis*s)   (coalesced copy-major reads)
__global__ void k_combine(const unsigned* __restrict__ pA, const float* __restrict__ s,
                          float2* __restrict__ sd, int N, int C) {
    int i = blockIdx.x * blockDim.x + threadIdx.x;
    if (i >= N) return;
    unsigned d = 1u;  // self-loop
    for (int c = 0; c < C; ++c) d += pA[(size_t)c * N + i];
    float dv = rsqrtf((float)d);
    sd[i] = make_float2(dv, dv * s[i]);
}

// K4: per-edge accumulation into LDS: up[r] += dis[c], vp[r] += dis[c]*s[c];
// plain coalesced slice writeback to pB[c][range] (float2 = (up, vp)).
__global__ __launch_bounds__(1024) void k_histB(const int* __restrict__ row,
                                                const int* __restrict__ col,
                                                const float2* __restrict__ sd,
                                                float2* __restrict__ pB,
                                                int E, int N, int C) {
    __shared__ float up[NRB];
    __shared__ float vp[NRB];
    int c = blockIdx.x / RB;
    int r = blockIdx.x % RB;
    int lo = r * NRB;
    int hi = lo + NRB; if (hi > N) hi = N;
    int len = hi - lo;
    for (int j = threadIdx.x; j < len; j += 1024) { up[j] = 0.f; vp[j] = 0.f; }
    __syncthreads();
    int per = (E + C - 1) / C;
    int e0 = c * per;
    int e1 = e0 + per; if (e1 > E) e1 = E;
    for (int e = e0 + threadIdx.x; e < e1; e += 1024) {
        unsigned idx = (unsigned)(row[e] - lo);
        if (idx < (unsigned)len) {
            float2 v = sd[col[e]];         // (dis, sdis) gather, L2-resident 400KB
            atomicAdd(&up[idx], v.x);
            atomicAdd(&vp[idx], v.y);
        }
    }
    __syncthreads();
    float2* dst = pB + (size_t)c * N + lo;
    for (int j = threadIdx.x; j < len; j += 1024)
        dst[j] = make_float2(up[j], vp[j]);
}

// K5: T[i] = dis*(sum vp + sdis) ; W[i] = dis*(sum up + dis)   (self-loop folded)
__global__ void k_tw(const float2* __restrict__ pB, const float2* __restrict__ sd,
                     float* __restrict__ T, float* __restrict__ W, int N, int C) {
    int i = blockIdx.x * blockDim.x + threadIdx.x;
    if (i >= N) return;
    float su = 0.f, sv = 0.f;
    for (int c = 0; c < C; ++c) {
        float2 p = pB[(size_t)c * N + i];
        su += p.x; sv += p.y;
    }
    float2 d = sd[i];
    T[i] = d.x * (sv + d.y);
    W[i] = d.x * (su + d.x);
}

// K6: out[i][d] = a2[d]*T[i] + bias[d]*W[i]
__global__ void k_out(const float* __restrict__ T, const float* __restrict__ W,
                      const float* __restrict__ a2, const float* __restrict__ bias,
                      float* __restrict__ out, int n) {
    int wave = (blockIdx.x * blockDim.x + threadIdx.x) >> 6;
    int lane = threadIdx.x & 63;
    if (wave >= n) return;
    float tv = T[wave], wv = W[wave];
    float2 a2v = ((const float2*)a2)[lane];
    float2 bv  = ((const float2*)bias)[lane];
    float2 o;
    o.x = a2v.x * tv + bv.x * wv;
    o.y = a2v.y * tv + bv.y * wv;
    ((float2*)(out + (size_t)wave * DIM))[lane] = o;
}

extern "C" void kernel_launch(void* const* d_in, const int* in_sizes, int n_in,
                              void* d_out, int out_size, void* d_ws, size_t ws_size,
                              hipStream_t stream) {
    const float* x    = (const float*)d_in[0];
    const int*   ei   = (const int*)d_in[1];
    const float* a1   = (const float*)d_in[2];
    const float* a2   = (const float*)d_in[3];
    const float* bias = (const float*)d_in[4];
    float* out = (float*)d_out;

    int N = in_sizes[0] / DIM;
    int E = in_sizes[1] / 2;
    const int* row = ei;        // edge_index[0]
    const int* col = ei + E;    // edge_index[1]

    // chunk count sized from workspace: floats needed = 5N + C*N (pA) + 2*C*N (pB)
    long F = (long)(ws_size / 4);
    long c_fit = (F - 5L * N) / (3L * N);
    int C = (int)(c_fit < 32 ? c_fit : 32);
    if (C < 1) C = 1;

    // workspace layout (floats): s[N], sd[2N], T[N], W[N], pA[C*N] (uint), pB[2*C*N]
    float*    s  = (float*)d_ws;
    float2*   sd = (float2*)(s + N);
    float*    T  = (float*)(sd + N);
    float*    W  = T + N;
    unsigned* pA = (unsigned*)(W + N);
    float2*   pB = (float2*)(pA + (size_t)C * N);

    k_s<<<(N + 3) / 4, 256, 0, stream>>>(x, a1, s, N);
    k_histA<<<C * RA, 1024, 0, stream>>>(col, pA, E, N, C);
    k_combine<<<(N + 255) / 256, 256, 0, stream>>>(pA, s, sd, N, C);
    k_histB<<<C * RB, 1024, 0, stream>>>(row, col, sd, pB, E, N, C);
    k_tw<<<(N + 255) / 256, 256, 0, stream>>>(pB, sd, T, W, N, C);
    k_out<<<(N + 3) / 4, 256, 0, stream>>>(T, W, a2, bias, out, N);
}

// Round 4
// 48.727 us; speedup vs baseline: 2.5416x; 1.4493x over previous
//
#include <hip/hip_runtime.h>

#define DIM 128
#define CA 64          // edge chunks for degree histogram
#define RA 2           // node ranges (u16-packed, 25000 nodes = 50KB LDS)
#define NA 25000
#define CB 32          // edge chunks for weighted scatter
#define RB 8           // node ranges (2 x 6250 f32 = 50KB LDS)
#define NB 6250

// K1: s[i] = dot(x[i], a1). Wave handles 2 rows, float4 loads (16B/lane).
__global__ void k_s(const float* __restrict__ x, const float* __restrict__ a1,
                    float* __restrict__ s, int n) {
    int gtid = blockIdx.x * blockDim.x + threadIdx.x;
    int wave = gtid >> 6;
    int lane = threadIdx.x & 63;
    int j = lane & 31;
    int r = wave * 2 + (lane >> 5);
    if (r >= n) return;                       // n even: whole wave exits together
    float4 xv = ((const float4*)x)[(size_t)r * 32 + j];
    float4 av = ((const float4*)a1)[j];
    float p = xv.x * av.x + xv.y * av.y + xv.z * av.z + xv.w * av.w;
    #pragma unroll
    for (int off = 16; off > 0; off >>= 1)    // xor<32 stays within each half
        p += __shfl_xor(p, off, 64);
    if (j == 0) s[r] = p;
}

// K2: degree histogram of col. Block (c,rg): u16-packed LDS counts, one scan
// of chunk c, plain coalesced u32 slice writeback to pA[c][range].
__global__ __launch_bounds__(1024) void k_histA(const int* __restrict__ col,
                                                ushort* __restrict__ pA,
                                                int E, int N) {
    __shared__ unsigned h[NA / 2];            // 12500 words = 50KB
    int c  = blockIdx.x % CA;
    int rg = blockIdx.x / CA;
    int lo = rg * NA;
    for (int j = threadIdx.x; j < NA / 2; j += 1024) h[j] = 0u;
    __syncthreads();
    int per = (E + CA - 1) / CA;
    int e0 = c * per;
    int e1 = e0 + per; if (e1 > E) e1 = E;
    for (int e = e0 + threadIdx.x; e < e1; e += 1024) {
        unsigned idx = (unsigned)(col[e] - lo);
        if (idx < (unsigned)NA)
            atomicAdd(&h[idx >> 1], 1u << ((idx & 1) * 16));
    }
    __syncthreads();
    unsigned* dst = (unsigned*)(pA + (size_t)c * N + lo);   // lo, N even
    for (int j = threadIdx.x; j < NA / 2; j += 1024) dst[j] = h[j];
}

// K3: deg = 1 + sum_c pA[c][i]; sd[i] = (dis, dis*s)
__global__ void k_combine(const ushort* __restrict__ pA, const float* __restrict__ s,
                          float2* __restrict__ sd, int N) {
    int i = blockIdx.x * blockDim.x + threadIdx.x;
    if (i >= N) return;
    unsigned d = 1u;                          // self-loop
    #pragma unroll 8
    for (int c = 0; c < CA; ++c) d += pA[(size_t)c * N + i];
    float dv = rsqrtf((float)d);
    sd[i] = make_float2(dv, dv * s[i]);
}

// K4: weighted scatter. Block (c,rg): LDS accumulate up += dis[c], vp += sdis[c]
// for edges in chunk c with row in range rg; coalesced float2 slice writeback.
__global__ __launch_bounds__(1024) void k_histB(const int* __restrict__ row,
                                                const int* __restrict__ col,
                                                const float2* __restrict__ sd,
                                                float2* __restrict__ pB,
                                                int E, int N) {
    __shared__ float up[NB];
    __shared__ float vp[NB];
    int c  = blockIdx.x % CB;
    int rg = blockIdx.x / CB;
    int lo = rg * NB;
    for (int j = threadIdx.x; j < NB; j += 1024) { up[j] = 0.f; vp[j] = 0.f; }
    __syncthreads();
    int per = (E + CB - 1) / CB;
    int e0 = c * per;
    int e1 = e0 + per; if (e1 > E) e1 = E;
    for (int e = e0 + threadIdx.x; e < e1; e += 1024) {
        unsigned idx = (unsigned)(row[e] - lo);
        if (idx < (unsigned)NB) {
            float2 v = sd[col[e]];            // L2/L3-resident gather
            atomicAdd(&up[idx], v.x);
            atomicAdd(&vp[idx], v.y);
        }
    }
    __syncthreads();
    float2* dst = pB + (size_t)c * N + lo;
    for (int j = threadIdx.x; j < NB; j += 1024)
        dst[j] = make_float2(up[j], vp[j]);
}

// K5 (fused tw+out): wave handles 2 nodes. Lanes j=0..31 of each half hold
// copy j's partial, xor-reduce, then write the 128-float row as float4.
__global__ void k_out(const float2* __restrict__ pB, const float2* __restrict__ sd,
                      const float* __restrict__ a2, const float* __restrict__ bias,
                      float* __restrict__ out, int N) {
    int gtid = blockIdx.x * blockDim.x + threadIdx.x;
    int wave = gtid >> 6;
    int lane = threadIdx.x & 63;
    int j = lane & 31;
    int node = wave * 2 + (lane >> 5);
    if (node >= N) return;                    // N even: whole wave exits together
    float2 p = (j < CB) ? pB[(size_t)j * N + node] : make_float2(0.f, 0.f);
    float su = p.x, sv = p.y;
    #pragma unroll
    for (int off = 16; off > 0; off >>= 1) {
        su += __shfl_xor(su, off, 64);
        sv += __shfl_xor(sv, off, 64);
    }
    float2 d = sd[node];
    float T = d.x * (sv + d.y);               // + self-loop dis*sdis
    float W = d.x * (su + d.x);               // + self-loop dis*dis
    float4 a2v = ((const float4*)a2)[j];
    float4 bv  = ((const float4*)bias)[j];
    float4 o;
    o.x = a2v.x * T + bv.x * W;
    o.y = a2v.y * T + bv.y * W;
    o.z = a2v.z * T + bv.z * W;
    o.w = a2v.w * T + bv.w * W;
    ((float4*)out)[(size_t)node * 32 + j] = o;
}

extern "C" void kernel_launch(void* const* d_in, const int* in_sizes, int n_in,
                              void* d_out, int out_size, void* d_ws, size_t ws_size,
                              hipStream_t stream) {
    const float* x    = (const float*)d_in[0];
    const int*   ei   = (const int*)d_in[1];
    const float* a1   = (const float*)d_in[2];
    const float* a2   = (const float*)d_in[3];
    const float* bias = (const float*)d_in[4];
    float* out = (float*)d_out;

    int N = in_sizes[0] / DIM;   // 50000
    int E = in_sizes[1] / 2;     // 600000
    const int* row = ei;         // edge_index[0]
    const int* col = ei + E;     // edge_index[1]

    // workspace: s[N] f32, sd[N] float2, pA[CA*N] u16, pB[CB*N] float2  (~20MB)
    float*  s  = (float*)d_ws;
    float2* sd = (float2*)(s + N);
    ushort* pA = (ushort*)(sd + N);
    float2* pB = (float2*)(pA + (size_t)CA * N);

    k_s      <<<(N / 2 + 3) / 4,       256,  0, stream>>>(x, a1, s, N);
    k_histA  <<<CA * RA,               1024, 0, stream>>>(col, pA, E, N);
    k_combine<<<(N + 255) / 256,       256,  0, stream>>>(pA, s, sd, N);
    k_histB  <<<CB * RB,               1024, 0, stream>>>(row, col, sd, pB, E, N);
    k_out    <<<(N / 2 + 3) / 4,       256,  0, stream>>>(pB, sd, a2, bias, out, N);
}

// Round 5
// 42.689 us; speedup vs baseline: 2.9010x; 1.1414x over previous
//
#include <hip/hip_runtime.h>

#define DIM 128
#define CA 64          // edge chunks for degree histogram
#define RA 2           // node ranges (u16-packed, 25000 nodes = 50KB LDS)
#define NA 25000
#define HIST_BLOCKS (CA * RA)   // 128
#define CB 32          // edge chunks for weighted scatter
#define RB 8           // node ranges (2 x 6250 f32 = 50KB LDS)
#define NB 6250

// K1 (fused): blocks [0,HIST_BLOCKS) build the u16-packed degree histogram of
// col; remaining blocks compute s[i] = dot(x[i], a1) (2 rows/wave, float4).
__global__ __launch_bounds__(1024) void k1_hist_s(
        const float* __restrict__ x, const float* __restrict__ a1,
        const int* __restrict__ col, ushort* __restrict__ pA,
        float* __restrict__ s, int E, int N) {
    __shared__ unsigned h[NA / 2];            // 50KB
    if (blockIdx.x < HIST_BLOCKS) {
        int c  = blockIdx.x % CA;
        int rg = blockIdx.x / CA;
        int lo = rg * NA;
        for (int j = threadIdx.x; j < NA / 2; j += 1024) h[j] = 0u;
        __syncthreads();
        int per = (E + CA - 1) / CA;
        int e0 = c * per;
        int e1 = e0 + per; if (e1 > E) e1 = E;
        for (int e = e0 + threadIdx.x; e < e1; e += 1024) {
            unsigned idx = (unsigned)(col[e] - lo);
            if (idx < (unsigned)NA)
                atomicAdd(&h[idx >> 1], 1u << ((idx & 1) * 16));
        }
        __syncthreads();
        unsigned* dst = (unsigned*)(pA + (size_t)c * N + lo);   // lo, N even
        for (int j = threadIdx.x; j < NA / 2; j += 1024) dst[j] = h[j];
    } else {
        int lw   = threadIdx.x >> 6;          // 16 waves/block
        int lane = threadIdx.x & 63;
        int j    = lane & 31;
        int r = ((int)blockIdx.x - HIST_BLOCKS) * 32 + lw * 2 + (lane >> 5);
        if (r >= N) return;
        float4 xv = ((const float4*)x)[(size_t)r * 32 + j];
        float4 av = ((const float4*)a1)[j];
        float p = xv.x * av.x + xv.y * av.y + xv.z * av.z + xv.w * av.w;
        #pragma unroll
        for (int off = 16; off > 0; off >>= 1)
            p += __shfl_xor(p, off, 64);
        if (j == 0) s[r] = p;
    }
}

// K2: deg = 1 + sum_c pA[c][i]; sd[i] = (dis, dis*s)
__global__ void k_combine(const ushort* __restrict__ pA, const float* __restrict__ s,
                          float2* __restrict__ sd, int N) {
    int i = blockIdx.x * blockDim.x + threadIdx.x;
    if (i >= N) return;
    unsigned d = 1u;                          // self-loop
    #pragma unroll 8
    for (int c = 0; c < CA; ++c) d += pA[(size_t)c * N + i];
    float dv = rsqrtf((float)d);
    sd[i] = make_float2(dv, dv * s[i]);
}

// K3: weighted scatter. Block (c,rg): LDS accumulate up += dis[c], vp += sdis[c]
// for edges in chunk c with row in range rg; coalesced float2 slice writeback.
__global__ __launch_bounds__(1024) void k_histB(const int* __restrict__ row,
                                                const int* __restrict__ col,
                                                const float2* __restrict__ sd,
                                                float2* __restrict__ pB,
                                                int E, int N) {
    __shared__ float up[NB];
    __shared__ float vp[NB];
    int c  = blockIdx.x % CB;
    int rg = blockIdx.x / CB;
    int lo = rg * NB;
    for (int j = threadIdx.x; j < NB; j += 1024) { up[j] = 0.f; vp[j] = 0.f; }
    __syncthreads();
    int per = (E + CB - 1) / CB;
    int e0 = c * per;
    int e1 = e0 + per; if (e1 > E) e1 = E;
    for (int e = e0 + threadIdx.x; e < e1; e += 1024) {
        unsigned idx = (unsigned)(row[e] - lo);
        if (idx < (unsigned)NB) {
            float2 v = sd[col[e]];            // L2/L3-resident gather
            atomicAdd(&up[idx], v.x);
            atomicAdd(&vp[idx], v.y);
        }
    }
    __syncthreads();
    float2* dst = pB + (size_t)c * N + lo;
    for (int j = threadIdx.x; j < NB; j += 1024)
        dst[j] = make_float2(up[j], vp[j]);
}

// K4: two-phase. Phase 1: thread i reduces node i over CB copies (coalesced),
// T/W -> LDS. Phase 2: 32-lane groups write whole 512B rows as float4.
__global__ __launch_bounds__(256) void k_out(
        const float2* __restrict__ pB, const float2* __restrict__ sd,
        const float* __restrict__ a2, const float* __restrict__ bias,
        float* __restrict__ out, int N) {
    __shared__ float sT[256];
    __shared__ float sW[256];
    int base = blockIdx.x * 256;
    int i = base + threadIdx.x;
    if (i < N) {
        float su = 0.f, sv = 0.f;
        #pragma unroll 8
        for (int c = 0; c < CB; ++c) {
            float2 p = pB[(size_t)c * N + i];
            su += p.x; sv += p.y;
        }
        float2 d = sd[i];
        sT[threadIdx.x] = d.x * (sv + d.y);   // + self-loop dis*sdis
        sW[threadIdx.x] = d.x * (su + d.x);   // + self-loop dis*dis
    }
    __syncthreads();
    int j   = threadIdx.x & 31;
    int grp = threadIdx.x >> 5;               // 8 groups of 32 lanes
    float4 a2v = ((const float4*)a2)[j];
    float4 bv  = ((const float4*)bias)[j];
    #pragma unroll 4
    for (int rep = 0; rep < 32; ++rep) {
        int rl = rep * 8 + grp;
        int node = base + rl;
        if (node >= N) break;
        float T = sT[rl], W = sW[rl];
        float4 o;
        o.x = a2v.x * T + bv.x * W;
        o.y = a2v.y * T + bv.y * W;
        o.z = a2v.z * T + bv.z * W;
        o.w = a2v.w * T + bv.w * W;
        ((float4*)out)[(size_t)node * 32 + j] = o;
    }
}

extern "C" void kernel_launch(void* const* d_in, const int* in_sizes, int n_in,
                              void* d_out, int out_size, void* d_ws, size_t ws_size,
                              hipStream_t stream) {
    const float* x    = (const float*)d_in[0];
    const int*   ei   = (const int*)d_in[1];
    const float* a1   = (const float*)d_in[2];
    const float* a2   = (const float*)d_in[3];
    const float* bias = (const float*)d_in[4];
    float* out = (float*)d_out;

    int N = in_sizes[0] / DIM;   // 50000
    int E = in_sizes[1] / 2;     // 600000
    const int* row = ei;         // edge_index[0]
    const int* col = ei + E;     // edge_index[1]

    // workspace: s[N] f32, sd[N] float2, pA[CA*N] u16, pB[CB*N] float2 (~19.8MB)
    float*  s  = (float*)d_ws;
    float2* sd = (float2*)(s + N);
    ushort* pA = (ushort*)(sd + N);
    float2* pB = (float2*)(pA + (size_t)CA * N);

    int s_blocks = (N + 31) / 32;             // 32 rows per 1024-thread block
    k1_hist_s<<<HIST_BLOCKS + s_blocks, 1024, 0, stream>>>(x, a1, col, pA, s, E, N);
    k_combine<<<(N + 255) / 256, 256, 0, stream>>>(pA, s, sd, N);
    k_histB  <<<CB * RB, 1024, 0, stream>>>(row, col, sd, pB, E, N);
    k_out    <<<(N + 255) / 256, 256, 0, stream>>>(pB, sd, a2, bias, out, N);
}